// Round 5
// baseline (187.790 us; speedup 1.0000x reference)
//
#include <hip/hip_runtime.h>

typedef _Float16 f16;
typedef f16 f16x8 __attribute__((ext_vector_type(8)));
typedef f16 f16x4 __attribute__((ext_vector_type(4)));
typedef __fp16 fp16x2 __attribute__((ext_vector_type(2)));
typedef float f32x4 __attribute__((ext_vector_type(4)));
typedef float f32x16 __attribute__((ext_vector_type(16)));
typedef unsigned int u32;

#define NTOK 4096

// ---------------- f32 -> f16 convert ----------------
__global__ void k_f2h(const float* __restrict__ in, f16* __restrict__ out, int n) {
  int i = (blockIdx.x * blockDim.x + threadIdx.x) * 4;
  int stride = gridDim.x * blockDim.x * 4;
  for (; i < n; i += stride) {
    float4 f = *(const float4*)(in + i);
    f16x4 h;
    h[0] = (f16)f.x; h[1] = (f16)f.y; h[2] = (f16)f.z; h[3] = (f16)f.w;
    *(f16x4*)(out + i) = h;
  }
}

// ---------------- generic C = A[M,K] * W[NC,K]^T MFMA GEMM ----------------
__global__ __launch_bounds__(256) void k_gemm(
    const f16* __restrict__ A, const f16* __restrict__ W,
    int K, int mode,
    f16* __restrict__ Qb, f16* __restrict__ Kb, f16* __restrict__ Vtb,
    float* __restrict__ outF, const float* __restrict__ bias)
{
  __shared__ f16 Al[64 * 40];
  __shared__ f16 Wl[64 * 40];
  const int t = threadIdx.x;
  const int w = t >> 6, l = t & 63;
  const int lrow = l & 15, lk = l >> 4;
  const int m0 = blockIdx.y * 64, nc0 = blockIdx.x * 64;
  f32x4 acc[4] = {};
  const int srow = t >> 2, sseg = t & 3;
  for (int k0 = 0; k0 < K; k0 += 32) {
    __syncthreads();
    f16x8 av = *(const f16x8*)(A + (size_t)(m0 + srow) * K + k0 + sseg * 8);
    f16x8 wv = *(const f16x8*)(W + (size_t)(nc0 + srow) * K + k0 + sseg * 8);
    *(f16x8*)(Al + srow * 40 + sseg * 8) = av;
    *(f16x8*)(Wl + srow * 40 + sseg * 8) = wv;
    __syncthreads();
    f16x8 af = *(const f16x8*)(Al + (w * 16 + lrow) * 40 + lk * 8);
#pragma unroll
    for (int ct = 0; ct < 4; ++ct) {
      f16x8 bf = *(const f16x8*)(Wl + (ct * 16 + lrow) * 40 + lk * 8);
      acc[ct] = __builtin_amdgcn_mfma_f32_16x16x32_f16(af, bf, acc[ct], 0, 0, 0);
    }
  }
  const int nb = m0 + w * 16 + lk * 4;
  if (mode == 0) {
    const int b = nb >> 12, n = nb & 4095;
#pragma unroll
    for (int ct = 0; ct < 4; ++ct) {
      int gc = nc0 + ct * 16 + lrow;
      int s = gc >> 8, h = (gc >> 6) & 3, dd = gc & 63;
      int bh = b * 4 + h;
      if (s == 2) {
        f16x4 v;
#pragma unroll
        for (int j = 0; j < 4; ++j) v[j] = (f16)acc[ct][j];
        *(f16x4*)(Vtb + ((size_t)bh * 64 + dd) * 4096 + n) = v;
      } else {
        f16* dst = (s == 0) ? Qb : Kb;
#pragma unroll
        for (int j = 0; j < 4; ++j)
          dst[((size_t)bh * 4096 + n + j) * 64 + dd] = (f16)acc[ct][j];
      }
    }
  } else {
#pragma unroll
    for (int ct = 0; ct < 4; ++ct) {
      int gc = nc0 + ct * 16 + lrow;
      float bv = bias[gc];
#pragma unroll
      for (int j = 0; j < 4; ++j)
        outF[(size_t)(nb + j) * 256 + gc] = acc[ct][j] + bv;
    }
  }
}

// ---------------- per-channel L2 norm partials over token slices ----------------
__global__ __launch_bounds__(256) void k_norm1(
    const f16* __restrict__ Qb, const f16* __restrict__ Kb,
    float* __restrict__ partQ, float* __restrict__ partK)
{
  const int bh = blockIdx.x >> 5, slice = blockIdx.x & 31;
  const int t = threadIdx.x;
  const int dd = t & 63, part = t >> 6;
  const f16* qp = Qb + (size_t)bh * NTOK * 64;
  const f16* kp = Kb + (size_t)bh * NTOK * 64;
  const int nlo = slice * 128;
  float sq = 0.f, sk = 0.f;
  for (int n = nlo + part; n < nlo + 128; n += 4) {
    float q = (float)qp[(size_t)n * 64 + dd];
    float k = (float)kp[(size_t)n * 64 + dd];
    sq += q * q;
    sk += k * k;
  }
  __shared__ float rq[256], rk[256];
  rq[t] = sq; rk[t] = sk;
  __syncthreads();
  if (part == 0) {
    sq = rq[dd] + rq[64 + dd] + rq[128 + dd] + rq[192 + dd];
    sk = rk[dd] + rk[64 + dd] + rk[128 + dd] + rk[192 + dd];
    partQ[(bh * 32 + slice) * 64 + dd] = sq;
    partK[(bh * 32 + slice) * 64 + dd] = sk;
  }
}

// ---------------- finalize inv norms (log2e*temp folded into invq) ----------------
__global__ __launch_bounds__(512) void k_norm2(
    const float* __restrict__ partQ, const float* __restrict__ partK,
    const float* __restrict__ temp,
    float* __restrict__ invq, float* __restrict__ invk)
{
  const int t = threadIdx.x;
  const int bh = t >> 6, dd = t & 63;
  float sq = 0.f, sk = 0.f;
#pragma unroll
  for (int s = 0; s < 32; ++s) {
    sq += partQ[(bh * 32 + s) * 64 + dd];
    sk += partK[(bh * 32 + s) * 64 + dd];
  }
  invq[t] = temp[bh & 3] * 1.4426950408889634f / fmaxf(sqrtf(sq), 1e-12f);
  invk[t] = 1.0f / fmaxf(sqrtf(sk), 1e-12f);
}

// ---------------- in-place scale of Q,K by inv norms ----------------
__global__ void k_scale(f16* __restrict__ Qb, f16* __restrict__ Kb,
                        const float* __restrict__ invq, const float* __restrict__ invk) {
  const int vi = blockIdx.x * blockDim.x + threadIdx.x;
  const int e = vi * 8;
  const int bh = e >> 18, dd0 = e & 63;
  const float* iq = invq + bh * 64 + dd0;
  const float* ik = invk + bh * 64 + dd0;
  f16x8 q = *(f16x8*)(Qb + e);
  f16x8 k = *(f16x8*)(Kb + e);
#pragma unroll
  for (int j = 0; j < 8; ++j) {
    q[j] = (f16)((float)q[j] * iq[j]);
    k[j] = (f16)((float)k[j] * ik[j]);
  }
  *(f16x8*)(Qb + e) = q;
  *(f16x8*)(Kb + e) = k;
}

// ---------------- flash attention: LDS-free main loop, direct-L2 operands ----
// Block = 4 waves = 4 kh key-quarters of one 32-query tile. Each wave:
// 32 stages of 32 keys. S^T = mfma(K,Q); P in-register via cvt_pkrtz +
// v_permlane32_swap_b32; O,ls combined across kh once at the end via LDS.
__device__ inline void plane_swap(u32& a, u32& b) {
  asm volatile("v_permlane32_swap_b32 %0, %1" : "+v"(a), "+v"(b));
}

__device__ __forceinline__ void flash_step(
    const f16x8& k0, const f16x8& k1, const f16x8& k2, const f16x8& k3,
    const f16x8& v0, const f16x8& v1, const f16x8& v2, const f16x8& v3,
    const f16x8& qf0, const f16x8& qf1, const f16x8& qf2, const f16x8& qf3,
    f32x16& oacc0, f32x16& oacc1, float& lsw)
{
  f32x16 sacc = {};
  sacc = __builtin_amdgcn_mfma_f32_32x32x16_f16(k0, qf0, sacc, 0, 0, 0);
  sacc = __builtin_amdgcn_mfma_f32_32x32x16_f16(k1, qf1, sacc, 0, 0, 0);
  sacc = __builtin_amdgcn_mfma_f32_32x32x16_f16(k2, qf2, sacc, 0, 0, 0);
  sacc = __builtin_amdgcn_mfma_f32_32x32x16_f16(k3, qf3, sacc, 0, 0, 0);
  u32 Dw[8];
#pragma unroll
  for (int u = 0; u < 4; ++u) {
#pragma unroll
    for (int v = 0; v < 2; ++v) {
      float a = exp2f(sacc[u * 4 + v * 2]);
      float b2 = exp2f(sacc[u * 4 + v * 2 + 1]);
      lsw += a + b2;
      union { fp16x2 h; u32 u; } cv;
      cv.h = __builtin_amdgcn_cvt_pkrtz(a, b2);
      Dw[u * 2 + v] = cv.u;
    }
  }
  plane_swap(Dw[0], Dw[2]);
  plane_swap(Dw[1], Dw[3]);
  plane_swap(Dw[4], Dw[6]);
  plane_swap(Dw[5], Dw[7]);
  union { f16x8 v; u32 d[4]; } p0, p1;
  p0.d[0] = Dw[0]; p0.d[1] = Dw[1]; p0.d[2] = Dw[2]; p0.d[3] = Dw[3];
  p1.d[0] = Dw[4]; p1.d[1] = Dw[5]; p1.d[2] = Dw[6]; p1.d[3] = Dw[7];
  oacc0 = __builtin_amdgcn_mfma_f32_32x32x16_f16(p0.v, v0, oacc0, 0, 0, 0);
  oacc0 = __builtin_amdgcn_mfma_f32_32x32x16_f16(p1.v, v1, oacc0, 0, 0, 0);
  oacc1 = __builtin_amdgcn_mfma_f32_32x32x16_f16(p0.v, v2, oacc1, 0, 0, 0);
  oacc1 = __builtin_amdgcn_mfma_f32_32x32x16_f16(p1.v, v3, oacc1, 0, 0, 0);
}

#define LOADK(D, I) { \
    const f16* kpi = kp + (size_t)(I) * 2048; \
    D##0 = *(const f16x8*)(kpi); \
    D##1 = *(const f16x8*)(kpi + 16); \
    D##2 = *(const f16x8*)(kpi + 32); \
    D##3 = *(const f16x8*)(kpi + 48); }

#define LOADV(D, I) { \
    const f16* vpi = vp + (size_t)(I) * 32; \
    D##0 = *(const f16x8*)(vpi); \
    D##1 = *(const f16x8*)(vpi + 16); \
    D##2 = *(const f16x8*)(vpi + 32 * 4096); \
    D##3 = *(const f16x8*)(vpi + 32 * 4096 + 16); }

__global__ __launch_bounds__(256, 4) void k_flash2(
    const f16* __restrict__ Qb, const f16* __restrict__ Kb,
    const f16* __restrict__ Vtb, f16* __restrict__ Y)
{
  __shared__ float Osh[3 * 64 * 33];  // kh=1..3 partial O, [dd][n], stride 33
  __shared__ float Lsh[4 * 32];       // per-kh row sums
  const int t = threadIdx.x, kh = t >> 6, l = t & 63;
  const int r = l & 31, hi = l >> 5;
  // XCD-bijective swizzle: 1024 blocks, each XCD owns one (b,h)
  int nb2 = (blockIdx.x & 7) * 128 + (blockIdx.x >> 3);
  const int bh = nb2 >> 7, qt = nb2 & 127;
  const size_t base = (size_t)bh * NTOK * 64;
  const int nrow = qt * 32 + r;
  const f16* qp = Qb + base + (size_t)nrow * 64 + hi * 8;
  f16x8 qf0 = *(const f16x8*)(qp);
  f16x8 qf1 = *(const f16x8*)(qp + 16);
  f16x8 qf2 = *(const f16x8*)(qp + 32);
  f16x8 qf3 = *(const f16x8*)(qp + 48);
  // K: lane reads its A-frag row (kh*1024 + stage*32 + r)
  const f16* kp = Kb + base + (size_t)(kh * 1024 + r) * 64 + hi * 8;
  // V: lane reads B-frag rows dd=r and dd=32+r at this wave's m-range
  const f16* vp = Vtb + base + (size_t)r * 4096 + kh * 1024 + hi * 8;
  f32x16 oacc0 = {}, oacc1 = {};
  float lsw = 0.f;
  f16x8 kA0, kA1, kA2, kA3, kB0, kB1, kB2, kB3;
  f16x8 vA0, vA1, vA2, vA3, vB0, vB1, vB2, vB3;
  LOADK(kA, 0);
  for (int i = 0; i < 32; i += 2) {
    LOADV(vA, i);
    LOADK(kB, i + 1);
    flash_step(kA0, kA1, kA2, kA3, vA0, vA1, vA2, vA3,
               qf0, qf1, qf2, qf3, oacc0, oacc1, lsw);
    LOADV(vB, i + 1);
    LOADK(kA, i + 2);  // i=30 overshoots into adjacent ws buffers: benign, unused
    flash_step(kB0, kB1, kB2, kB3, vB0, vB1, vB2, vB3,
               qf0, qf1, qf2, qf3, oacc0, oacc1, lsw);
  }
  // ls: combine hi halves; publish per-kh
  lsw += __shfl_xor(lsw, 32, 64);
  if (hi == 0) Lsh[kh * 32 + r] = lsw;
  if (kh != 0) {
#pragma unroll
    for (int dt = 0; dt < 2; ++dt) {
      float* orow = Osh + ((kh - 1) * 64 + dt * 32 + r) * 33;
      const f32x16& oa = dt ? oacc1 : oacc0;
#pragma unroll
      for (int u = 0; u < 4; ++u) {
        f32x4 q4;
        q4[0] = oa[u * 4 + 0]; q4[1] = oa[u * 4 + 1];
        q4[2] = oa[u * 4 + 2]; q4[3] = oa[u * 4 + 3];
        *(f32x4*)(orow + u * 8 + hi * 4) = q4;
      }
    }
  }
  __syncthreads();
  if (kh == 0) {
    const int b = bh >> 2, h = bh & 3;
#pragma unroll
    for (int dt = 0; dt < 2; ++dt) {
      const int dd = dt * 32 + r;
      const float* o1 = Osh + (dd) * 33;
      const float* o2 = Osh + (64 + dd) * 33;
      const float* o3 = Osh + (128 + dd) * 33;
      const f32x16& oa = dt ? oacc1 : oacc0;
#pragma unroll
      for (int u = 0; u < 4; ++u) {
        const int off = u * 8 + hi * 4;
        f32x4 p1 = *(const f32x4*)(o1 + off);
        f32x4 p2 = *(const f32x4*)(o2 + off);
        f32x4 p3 = *(const f32x4*)(o3 + off);
        f32x4 l0 = *(const f32x4*)(Lsh + off);
        f32x4 l1 = *(const f32x4*)(Lsh + 32 + off);
        f32x4 l2 = *(const f32x4*)(Lsh + 64 + off);
        f32x4 l3 = *(const f32x4*)(Lsh + 96 + off);
        const int ng = qt * 32 + off;          // first of 4 query rows
        const int np = dd * 64 + h * 16 + (ng >> 8);
        const int cp = ng & 255;
        f16x4 yv;
#pragma unroll
        for (int j = 0; j < 4; ++j) {
          float num = oa[u * 4 + j] + p1[j] + p2[j] + p3[j];
          float den = l0[j] + l1[j] + l2[j] + l3[j];
          yv[j] = (f16)(num / den);
        }
        *(f16x4*)(Y + ((size_t)b * 4096 + np) * 256 + cp) = yv;
      }
    }
  }
}

extern "C" void kernel_launch(void* const* d_in, const int* in_sizes, int n_in,
                              void* d_out, int out_size, void* d_ws, size_t ws_size,
                              hipStream_t stream)
{
  const float* x     = (const float*)d_in[0];   // [2,4096,256]
  const float* w_qkv = (const float*)d_in[1];   // [768,256]
  const float* w_out = (const float*)d_in[2];   // [256,256]
  const float* b_out = (const float*)d_in[3];   // [256]
  const float* temp  = (const float*)d_in[4];   // [4,1,1]

  char* ws = (char*)d_ws;
  f16*   xb    = (f16*)(ws);                                  // 4MB
  f16*   wqkvb = (f16*)(ws + 4 * 1024 * 1024);
  f16*   woutb = (f16*)(ws + 4 * 1024 * 1024 + 512 * 1024);
  f16*   Qb    = (f16*)(ws + 5  * 1024 * 1024);               // [8][4096][64]
  f16*   Kb    = (f16*)(ws + 9  * 1024 * 1024);
  f16*   Vtb   = (f16*)(ws + 13 * 1024 * 1024);               // [8][64][4096]
  float* invq  = (float*)(ws + 17 * 1024 * 1024);
  float* invk  = (float*)(ws + 17 * 1024 * 1024 + 4096);
  float* partQ = (float*)(ws + 17 * 1024 * 1024 + 8192);
  float* partK = (float*)(ws + 17 * 1024 * 1024 + 8192 + 65536);
  f16*   Y     = (f16*)(ws + 18 * 1024 * 1024);               // [2][4096][256]
  float* outF  = (float*)d_out;

  k_f2h<<<2048, 256, 0, stream>>>(x, xb, 2 * 4096 * 256);
  k_f2h<<<192, 256, 0, stream>>>(w_qkv, wqkvb, 768 * 256);
  k_f2h<<<64, 256, 0, stream>>>(w_out, woutb, 256 * 256);
  k_gemm<<<dim3(12, 128), 256, 0, stream>>>(xb, wqkvb, 256, 0, Qb, Kb, Vtb, nullptr, nullptr);
  k_norm1<<<256, 256, 0, stream>>>(Qb, Kb, partQ, partK);
  k_norm2<<<1, 512, 0, stream>>>(partQ, partK, temp, invq, invk);
  k_scale<<<1024, 256, 0, stream>>>(Qb, Kb, invq, invk);
  k_flash2<<<1024, 256, 0, stream>>>(Qb, Kb, Vtb, Y);
  k_gemm<<<dim3(4, 128), 256, 0, stream>>>(Y, woutb, 256, 1, nullptr, nullptr, nullptr, outF, b_out);
}

// Round 6
// 123.624 us; speedup vs baseline: 1.5190x; 1.5190x over previous
//
#include <hip/hip_runtime.h>

typedef _Float16 f16;
typedef f16 f16x8 __attribute__((ext_vector_type(8)));
typedef f16 f16x4 __attribute__((ext_vector_type(4)));
typedef __fp16 fp16x2 __attribute__((ext_vector_type(2)));
typedef float f32x4 __attribute__((ext_vector_type(4)));
typedef float f32x16 __attribute__((ext_vector_type(16)));
typedef unsigned int u32;

#define NTOK 4096

// async global->LDS, 16B per lane; dest = uniform base + lane*16
#define GLL(gsrc, ldst) \
  __builtin_amdgcn_global_load_lds( \
      (const __attribute__((address_space(1))) void*)(gsrc), \
      (__attribute__((address_space(3))) void*)(ldst), 16, 0, 0)

// ---------------- f32 -> f16 convert ----------------
__global__ void k_f2h(const float* __restrict__ in, f16* __restrict__ out, int n) {
  int i = (blockIdx.x * blockDim.x + threadIdx.x) * 4;
  int stride = gridDim.x * blockDim.x * 4;
  for (; i < n; i += stride) {
    float4 f = *(const float4*)(in + i);
    f16x4 h;
    h[0] = (f16)f.x; h[1] = (f16)f.y; h[2] = (f16)f.z; h[3] = (f16)f.w;
    *(f16x4*)(out + i) = h;
  }
}

// ---------------- generic C = A[M,K] * W[NC,K]^T MFMA GEMM ----------------
__global__ __launch_bounds__(256) void k_gemm(
    const f16* __restrict__ A, const f16* __restrict__ W,
    int K, int mode,
    f16* __restrict__ Qb, f16* __restrict__ Kb, f16* __restrict__ Vtb,
    float* __restrict__ outF, const float* __restrict__ bias)
{
  __shared__ f16 Al[64 * 40];
  __shared__ f16 Wl[64 * 40];
  const int t = threadIdx.x;
  const int w = t >> 6, l = t & 63;
  const int lrow = l & 15, lk = l >> 4;
  const int m0 = blockIdx.y * 64, nc0 = blockIdx.x * 64;
  f32x4 acc[4] = {};
  const int srow = t >> 2, sseg = t & 3;
  for (int k0 = 0; k0 < K; k0 += 32) {
    __syncthreads();
    f16x8 av = *(const f16x8*)(A + (size_t)(m0 + srow) * K + k0 + sseg * 8);
    f16x8 wv = *(const f16x8*)(W + (size_t)(nc0 + srow) * K + k0 + sseg * 8);
    *(f16x8*)(Al + srow * 40 + sseg * 8) = av;
    *(f16x8*)(Wl + srow * 40 + sseg * 8) = wv;
    __syncthreads();
    f16x8 af = *(const f16x8*)(Al + (w * 16 + lrow) * 40 + lk * 8);
#pragma unroll
    for (int ct = 0; ct < 4; ++ct) {
      f16x8 bf = *(const f16x8*)(Wl + (ct * 16 + lrow) * 40 + lk * 8);
      acc[ct] = __builtin_amdgcn_mfma_f32_16x16x32_f16(af, bf, acc[ct], 0, 0, 0);
    }
  }
  const int nb = m0 + w * 16 + lk * 4;
  if (mode == 0) {
    const int b = nb >> 12, n = nb & 4095;
#pragma unroll
    for (int ct = 0; ct < 4; ++ct) {
      int gc = nc0 + ct * 16 + lrow;
      int s = gc >> 8, h = (gc >> 6) & 3, dd = gc & 63;
      int bh = b * 4 + h;
      if (s == 2) {
        f16x4 v;
#pragma unroll
        for (int j = 0; j < 4; ++j) v[j] = (f16)acc[ct][j];
        *(f16x4*)(Vtb + ((size_t)bh * 64 + dd) * 4096 + n) = v;
      } else {
        f16* dst = (s == 0) ? Qb : Kb;
#pragma unroll
        for (int j = 0; j < 4; ++j)
          dst[((size_t)bh * 4096 + n + j) * 64 + dd] = (f16)acc[ct][j];
      }
    }
  } else {
#pragma unroll
    for (int ct = 0; ct < 4; ++ct) {
      int gc = nc0 + ct * 16 + lrow;
      float bv = bias[gc];
#pragma unroll
      for (int j = 0; j < 4; ++j)
        outF[(size_t)(nb + j) * 256 + gc] = acc[ct][j] + bv;
    }
  }
}

// ---------------- per-channel L2 norm partials over token slices ----------------
__global__ __launch_bounds__(256) void k_norm1(
    const f16* __restrict__ Qb, const f16* __restrict__ Kb,
    float* __restrict__ partQ, float* __restrict__ partK)
{
  const int bh = blockIdx.x >> 5, slice = blockIdx.x & 31;
  const int t = threadIdx.x;
  const int dd = t & 63, part = t >> 6;
  const f16* qp = Qb + (size_t)bh * NTOK * 64;
  const f16* kp = Kb + (size_t)bh * NTOK * 64;
  const int nlo = slice * 128;
  float sq = 0.f, sk = 0.f;
  for (int n = nlo + part; n < nlo + 128; n += 4) {
    float q = (float)qp[(size_t)n * 64 + dd];
    float k = (float)kp[(size_t)n * 64 + dd];
    sq += q * q;
    sk += k * k;
  }
  __shared__ float rq[256], rk[256];
  rq[t] = sq; rk[t] = sk;
  __syncthreads();
  if (part == 0) {
    sq = rq[dd] + rq[64 + dd] + rq[128 + dd] + rq[192 + dd];
    sk = rk[dd] + rk[64 + dd] + rk[128 + dd] + rk[192 + dd];
    partQ[(bh * 32 + slice) * 64 + dd] = sq;
    partK[(bh * 32 + slice) * 64 + dd] = sk;
  }
}

// ---------------- finalize: combined Q-side scale c = temp*log2e/(|q||k|) ----
__global__ __launch_bounds__(512) void k_norm2(
    const float* __restrict__ partQ, const float* __restrict__ partK,
    const float* __restrict__ temp, f16* __restrict__ cqh)
{
  const int t = threadIdx.x;            // 512 = 8 bh * 64 dd
  const int bh = t >> 6;
  float sq = 0.f, sk = 0.f;
#pragma unroll
  for (int s = 0; s < 32; ++s) {
    sq += partQ[bh * 2048 + s * 64 + (t & 63)];
    sk += partK[bh * 2048 + s * 64 + (t & 63)];
  }
  float c = temp[bh & 3] * 1.4426950408889634f /
            (fmaxf(sqrtf(sq), 1e-12f) * fmaxf(sqrtf(sk), 1e-12f));
  cqh[t] = (f16)c;
}

// ---------------- flash attention v3: 8 waves, LDS-staged via global_load_lds -
// Block = 64 queries (qs halves) x full keys; waves (qs,kh): qs=w&1, kh=w>>1.
// 32 stages of 128-key K/V tiles in 32KB LDS (linear dest, source pre-swizzled,
// XOR-swizzled reads).  S^T = mfma(K,Q); P in-register (cvt_pkrtz+permlane32);
// kh-partials combined through f16 LDS (aliased onto staging buffer).
__device__ inline void plane_swap(u32& a, u32& b) {
  asm volatile("v_permlane32_swap_b32 %0, %1" : "+v"(a), "+v"(b));
}

__global__ __launch_bounds__(512, 4) void k_flash3(
    const f16* __restrict__ Qb, const f16* __restrict__ Kb,
    const f16* __restrict__ Vtb, const f16* __restrict__ cqh,
    f16* __restrict__ Y)
{
  __shared__ f16 KVl[16384];   // Kl [128 keys][64 d] | Vl [64 dd][128 keys]
  __shared__ float Lsh[256];   // [(qs*4+kh)*32 + n]
  f16* Kl = KVl;
  f16* Vl = KVl + 8192;
  f16* OshH = KVl;             // alias (reused after post-loop barrier):
                               // [((qs*3 + kh-1)*64 + dd)*32 + n] f16, 24KB
  const int t = threadIdx.x, w = t >> 6, l = t & 63;
  const int r = l & 31, hi = l >> 5;
  const int qs = w & 1, kh = w >> 1;
  // XCD-bijective swizzle: 512 blocks, each XCD owns one (b,h)
  int nb2 = (blockIdx.x & 7) * 64 + (blockIdx.x >> 3);
  const int bh = nb2 >> 6, qt = nb2 & 63;
  const size_t base = (size_t)bh * NTOK * 64;
  const int nrow = qt * 64 + qs * 32 + r;
  // Q B-fragments, scaled by combined per-d factor c
  const f16* qp = Qb + base + (size_t)nrow * 64 + hi * 8;
  const f16* cp = cqh + bh * 64 + hi * 8;
  f16x8 qf0 = *(const f16x8*)(qp)      * *(const f16x8*)(cp);
  f16x8 qf1 = *(const f16x8*)(qp + 16) * *(const f16x8*)(cp + 16);
  f16x8 qf2 = *(const f16x8*)(qp + 32) * *(const f16x8*)(cp + 32);
  f16x8 qf3 = *(const f16x8*)(qp + 48) * *(const f16x8*)(cp + 48);
  // staging roles: waves 0-3 stage K (32 rows each), waves 4-7 stage V (16 dd rows)
  // K lane map (instr j): row = w*32 + j*8 + l/8, chunk(l%8) <- global chunk (l%8)^(l/8)
  const f16* gK = Kb + base + (size_t)(w * 32 + (l >> 3)) * 64 + ((l & 7) ^ (l >> 3)) * 8;
  f16* lK = Kl + w * 2048;
  // V lane map (instr j): dd = (w-4)*16 + j*4 + l/16, chunk(l%16) <- global (l%16)^(dd&7)
  const int wv = w - 4;
  const int vdd0 = wv * 16 + (l >> 4);
  const f16* gV0 = Vtb + base + (size_t)(vdd0)      * 4096 + (((l & 15) ^ ((vdd0)      & 7)) * 8);
  const f16* gV1 = Vtb + base + (size_t)(vdd0 + 4)  * 4096 + (((l & 15) ^ ((vdd0 + 4)  & 7)) * 8);
  const f16* gV2 = Vtb + base + (size_t)(vdd0 + 8)  * 4096 + (((l & 15) ^ ((vdd0 + 8)  & 7)) * 8);
  const f16* gV3 = Vtb + base + (size_t)(vdd0 + 12) * 4096 + (((l & 15) ^ ((vdd0 + 12) & 7)) * 8);
  f16* lV = Vl + wv * 2048;
  // fragment read pointers (constant across stages; XOR-swizzled)
  const int r7 = r & 7;
  const f16* kf0p = Kl + (kh * 32 + r) * 64 + (((0 + hi) ^ r7) * 8);
  const f16* kf1p = Kl + (kh * 32 + r) * 64 + (((2 + hi) ^ r7) * 8);
  const f16* kf2p = Kl + (kh * 32 + r) * 64 + (((4 + hi) ^ r7) * 8);
  const f16* kf3p = Kl + (kh * 32 + r) * 64 + (((6 + hi) ^ r7) * 8);
  const f16* vf00p = Vl + (r)      * 128 + (((kh * 4 + 0 + hi) ^ r7) * 8);
  const f16* vf01p = Vl + (r)      * 128 + (((kh * 4 + 2 + hi) ^ r7) * 8);
  const f16* vf10p = Vl + (32 + r) * 128 + (((kh * 4 + 0 + hi) ^ r7) * 8);
  const f16* vf11p = Vl + (32 + r) * 128 + (((kh * 4 + 2 + hi) ^ r7) * 8);

  f32x16 oacc0 = {}, oacc1 = {};
  float lsw = 0.f;
  for (int s = 0; s < 32; ++s) {
    __syncthreads();
    if (w < 4) {
      GLL(gK,        lK);
      GLL(gK +  512, lK +  512);
      GLL(gK + 1024, lK + 1024);
      GLL(gK + 1536, lK + 1536);
      gK += 8192;                 // next 128 keys
    } else {
      GLL(gV0, lV);
      GLL(gV1, lV +  512);
      GLL(gV2, lV + 1024);
      GLL(gV3, lV + 1536);
      gV0 += 128; gV1 += 128; gV2 += 128; gV3 += 128;
    }
    __syncthreads();
    // S^T = K . Q^T over this wave's 32-key slice
    f32x16 sacc = {};
    sacc = __builtin_amdgcn_mfma_f32_32x32x16_f16(*(const f16x8*)kf0p, qf0, sacc, 0, 0, 0);
    sacc = __builtin_amdgcn_mfma_f32_32x32x16_f16(*(const f16x8*)kf1p, qf1, sacc, 0, 0, 0);
    sacc = __builtin_amdgcn_mfma_f32_32x32x16_f16(*(const f16x8*)kf2p, qf2, sacc, 0, 0, 0);
    sacc = __builtin_amdgcn_mfma_f32_32x32x16_f16(*(const f16x8*)kf3p, qf3, sacc, 0, 0, 0);
    // P = exp2(S^T); pack; redistribute to A-frag layout
    u32 Dw[8];
#pragma unroll
    for (int u = 0; u < 4; ++u) {
#pragma unroll
      for (int v = 0; v < 2; ++v) {
        float a  = exp2f(sacc[u * 4 + v * 2]);
        float b2 = exp2f(sacc[u * 4 + v * 2 + 1]);
        lsw += a + b2;
        union { fp16x2 h; u32 u; } cv;
        cv.h = __builtin_amdgcn_cvt_pkrtz(a, b2);
        Dw[u * 2 + v] = cv.u;
      }
    }
    plane_swap(Dw[0], Dw[2]);
    plane_swap(Dw[1], Dw[3]);
    plane_swap(Dw[4], Dw[6]);
    plane_swap(Dw[5], Dw[7]);
    union { f16x8 v; u32 d[4]; } p0, p1;
    p0.d[0] = Dw[0]; p0.d[1] = Dw[1]; p0.d[2] = Dw[2]; p0.d[3] = Dw[3];
    p1.d[0] = Dw[4]; p1.d[1] = Dw[5]; p1.d[2] = Dw[6]; p1.d[3] = Dw[7];
    // O += P . V^T
    oacc0 = __builtin_amdgcn_mfma_f32_32x32x16_f16(p0.v, *(const f16x8*)vf00p, oacc0, 0, 0, 0);
    oacc0 = __builtin_amdgcn_mfma_f32_32x32x16_f16(p1.v, *(const f16x8*)vf01p, oacc0, 0, 0, 0);
    oacc1 = __builtin_amdgcn_mfma_f32_32x32x16_f16(p0.v, *(const f16x8*)vf10p, oacc1, 0, 0, 0);
    oacc1 = __builtin_amdgcn_mfma_f32_32x32x16_f16(p1.v, *(const f16x8*)vf11p, oacc1, 0, 0, 0);
  }
  // combine ls across hi halves (same query col n=r)
  lsw += __shfl_xor(lsw, 32, 64);
  __syncthreads();   // staging LDS now free for O partials
  if (hi == 0) Lsh[(qs * 4 + kh) * 32 + r] = lsw;
  if (kh != 0) {
#pragma unroll
    for (int dt = 0; dt < 2; ++dt) {
      f16* orow = OshH + ((qs * 3 + kh - 1) * 64 + dt * 32 + r) * 32;
      const f32x16& oa = dt ? oacc1 : oacc0;
#pragma unroll
      for (int u = 0; u < 4; ++u) {
        f16x4 h4;
        h4[0] = (f16)oa[u * 4 + 0]; h4[1] = (f16)oa[u * 4 + 1];
        h4[2] = (f16)oa[u * 4 + 2]; h4[3] = (f16)oa[u * 4 + 3];
        *(f16x4*)(orow + u * 8 + hi * 4) = h4;
      }
    }
  }
  __syncthreads();
  if (kh == 0) {
    const int b = bh >> 2, h = bh & 3;
#pragma unroll
    for (int dt = 0; dt < 2; ++dt) {
      const int dd = dt * 32 + r;
      const f16* o1 = OshH + ((qs * 3 + 0) * 64 + dd) * 32;
      const f16* o2 = OshH + ((qs * 3 + 1) * 64 + dd) * 32;
      const f16* o3 = OshH + ((qs * 3 + 2) * 64 + dd) * 32;
      const f32x16& oa = dt ? oacc1 : oacc0;
#pragma unroll
      for (int u = 0; u < 4; ++u) {
        const int off = u * 8 + hi * 4;
        f16x4 p1 = *(const f16x4*)(o1 + off);
        f16x4 p2 = *(const f16x4*)(o2 + off);
        f16x4 p3 = *(const f16x4*)(o3 + off);
        f32x4 l0 = *(const f32x4*)(Lsh + qs * 128 + off);
        f32x4 l1 = *(const f32x4*)(Lsh + qs * 128 + 32 + off);
        f32x4 l2 = *(const f32x4*)(Lsh + qs * 128 + 64 + off);
        f32x4 l3 = *(const f32x4*)(Lsh + qs * 128 + 96 + off);
        const int ng = qt * 64 + qs * 32 + off;   // first of 4 query rows
        const int np = dd * 64 + h * 16 + (ng >> 8);
        const int cp_ = ng & 255;
        f16x4 yv;
#pragma unroll
        for (int j = 0; j < 4; ++j) {
          float num = oa[u * 4 + j] + (float)p1[j] + (float)p2[j] + (float)p3[j];
          float den = l0[j] + l1[j] + l2[j] + l3[j];
          yv[j] = (f16)(num / den);
        }
        *(f16x4*)(Y + ((size_t)b * 4096 + np) * 256 + cp_) = yv;
      }
    }
  }
}

extern "C" void kernel_launch(void* const* d_in, const int* in_sizes, int n_in,
                              void* d_out, int out_size, void* d_ws, size_t ws_size,
                              hipStream_t stream)
{
  const float* x     = (const float*)d_in[0];   // [2,4096,256]
  const float* w_qkv = (const float*)d_in[1];   // [768,256]
  const float* w_out = (const float*)d_in[2];   // [256,256]
  const float* b_out = (const float*)d_in[3];   // [256]
  const float* temp  = (const float*)d_in[4];   // [4,1,1]

  char* ws = (char*)d_ws;
  f16*   xb    = (f16*)(ws);                                  // 4MB
  f16*   wqkvb = (f16*)(ws + 4 * 1024 * 1024);
  f16*   woutb = (f16*)(ws + 4 * 1024 * 1024 + 512 * 1024);
  f16*   Qb    = (f16*)(ws + 5  * 1024 * 1024);               // [8][4096][64]
  f16*   Kb    = (f16*)(ws + 9  * 1024 * 1024);
  f16*   Vtb   = (f16*)(ws + 13 * 1024 * 1024);               // [8][64][4096]
  f16*   cqh   = (f16*)(ws + 17 * 1024 * 1024);               // 512 f16
  float* partQ = (float*)(ws + 17 * 1024 * 1024 + 8192);
  float* partK = (float*)(ws + 17 * 1024 * 1024 + 8192 + 65536);
  f16*   Y     = (f16*)(ws + 18 * 1024 * 1024);               // [2][4096][256]
  float* outF  = (float*)d_out;

  k_f2h<<<2048, 256, 0, stream>>>(x, xb, 2 * 4096 * 256);
  k_f2h<<<192, 256, 0, stream>>>(w_qkv, wqkvb, 768 * 256);
  k_f2h<<<64, 256, 0, stream>>>(w_out, woutb, 256 * 256);
  k_gemm<<<dim3(12, 128), 256, 0, stream>>>(xb, wqkvb, 256, 0, Qb, Kb, Vtb, nullptr, nullptr);
  k_norm1<<<256, 256, 0, stream>>>(Qb, Kb, partQ, partK);
  k_norm2<<<1, 512, 0, stream>>>(partQ, partK, temp, cqh);
  k_flash3<<<512, 512, 0, stream>>>(Qb, Kb, Vtb, cqh, Y);
  k_gemm<<<dim3(4, 128), 256, 0, stream>>>(Y, woutb, 256, 1, nullptr, nullptr, nullptr, outF, b_out);
}

// Round 7
// 96.785 us; speedup vs baseline: 1.9403x; 1.2773x over previous
//
#include <hip/hip_runtime.h>

typedef _Float16 f16;
typedef f16 f16x8 __attribute__((ext_vector_type(8)));
typedef f16 f16x4 __attribute__((ext_vector_type(4)));
typedef __fp16 fp16x2 __attribute__((ext_vector_type(2)));
typedef float f32x4 __attribute__((ext_vector_type(4)));
typedef float f32x16 __attribute__((ext_vector_type(16)));
typedef unsigned int u32;

#define NTOK 4096

// async global->LDS, 16B per lane; dest = wave-uniform base + lane*16
#define GLL(gsrc, ldst) \
  __builtin_amdgcn_global_load_lds( \
      (const __attribute__((address_space(1))) void*)(gsrc), \
      (__attribute__((address_space(3))) void*)(ldst), 16, 0, 0)

// ---------------- fused f32 -> f16 convert (x | w_qkv | w_out) ----------------
__global__ __launch_bounds__(256) void k_cvt(
    const float* __restrict__ x, const float* __restrict__ wq,
    const float* __restrict__ wo,
    f16* __restrict__ xb, f16* __restrict__ wqb, f16* __restrict__ wob)
{
  const int bx = blockIdx.x;
  const float* src; f16* dst; int off;
  if (bx < 2048)      { src = x;  dst = xb;  off = bx * 1024; }
  else if (bx < 2240) { src = wq; dst = wqb; off = (bx - 2048) * 1024; }
  else                { src = wo; dst = wob; off = (bx - 2240) * 1024; }
  const int i = off + threadIdx.x * 4;
  float4 f = *(const float4*)(src + i);
  f16x4 h;
  h[0] = (f16)f.x; h[1] = (f16)f.y; h[2] = (f16)f.z; h[3] = (f16)f.w;
  *(f16x4*)(dst + i) = h;
}

// ---------------- generic C = A[M,K] * W[NC,K]^T MFMA GEMM ----------------
// mode 0: QKV epilogue -> scatter to Qb/Kb/Vtb + fused norm partial sums (f32 acc)
// mode 1: out epilogue -> d_out f32 + bias
__global__ __launch_bounds__(256) void k_gemm(
    const f16* __restrict__ A, const f16* __restrict__ W,
    int K, int mode,
    f16* __restrict__ Qb, f16* __restrict__ Kb, f16* __restrict__ Vtb,
    float* __restrict__ outF, const float* __restrict__ bias,
    float* __restrict__ partQ, float* __restrict__ partK)
{
  __shared__ f16 Al[64 * 40];
  __shared__ f16 Wl[64 * 40];
  __shared__ float redl[4][64];
  const int t = threadIdx.x;
  const int w = t >> 6, l = t & 63;
  const int lrow = l & 15, lk = l >> 4;
  const int m0 = blockIdx.y * 64, nc0 = blockIdx.x * 64;
  f32x4 acc[4] = {};
  const int srow = t >> 2, sseg = t & 3;
  for (int k0 = 0; k0 < K; k0 += 32) {
    __syncthreads();
    f16x8 av = *(const f16x8*)(A + (size_t)(m0 + srow) * K + k0 + sseg * 8);
    f16x8 wv = *(const f16x8*)(W + (size_t)(nc0 + srow) * K + k0 + sseg * 8);
    *(f16x8*)(Al + srow * 40 + sseg * 8) = av;
    *(f16x8*)(Wl + srow * 40 + sseg * 8) = wv;
    __syncthreads();
    f16x8 af = *(const f16x8*)(Al + (w * 16 + lrow) * 40 + lk * 8);
#pragma unroll
    for (int ct = 0; ct < 4; ++ct) {
      f16x8 bf = *(const f16x8*)(Wl + (ct * 16 + lrow) * 40 + lk * 8);
      acc[ct] = __builtin_amdgcn_mfma_f32_16x16x32_f16(af, bf, acc[ct], 0, 0, 0);
    }
  }
  const int nb = m0 + w * 16 + lk * 4;
  if (mode == 0) {
    const int b = nb >> 12, n = nb & 4095;
#pragma unroll
    for (int ct = 0; ct < 4; ++ct) {
      int gc = nc0 + ct * 16 + lrow;
      int s = gc >> 8, h = (gc >> 6) & 3, dd = gc & 63;
      int bh = b * 4 + h;
      if (s == 2) {
        f16x4 v;
#pragma unroll
        for (int j = 0; j < 4; ++j) v[j] = (f16)acc[ct][j];
        *(f16x4*)(Vtb + ((size_t)bh * 64 + dd) * 4096 + n) = v;
      } else {
        f16* dst = (s == 0) ? Qb : Kb;
#pragma unroll
        for (int j = 0; j < 4; ++j)
          dst[((size_t)bh * 4096 + n + j) * 64 + dd] = (f16)acc[ct][j];
      }
    }
    // fused per-channel squared-sum partials (over this block's 64 tokens)
    if (nc0 < 512) {
#pragma unroll
      for (int ct = 0; ct < 4; ++ct) {
        float v = acc[ct][0] * acc[ct][0] + acc[ct][1] * acc[ct][1]
                + acc[ct][2] * acc[ct][2] + acc[ct][3] * acc[ct][3];
        v += __shfl_xor(v, 16, 64);
        v += __shfl_xor(v, 32, 64);
        if (lk == 0) redl[w][ct * 16 + lrow] = v;
      }
      __syncthreads();
      if (t < 64) {
        float sq = redl[0][t] + redl[1][t] + redl[2][t] + redl[3][t];
        const int s = nc0 >> 8, h2 = (nc0 >> 6) & 3;
        const int b2 = m0 >> 12, mb = (m0 >> 6) & 63;
        float* dst = (s == 0) ? partQ : partK;
        dst[((b2 * 4 + h2) * 64 + mb) * 64 + t] = sq;
      }
    }
  } else {
#pragma unroll
    for (int ct = 0; ct < 4; ++ct) {
      int gc = nc0 + ct * 16 + lrow;
      float bv = bias[gc];
#pragma unroll
      for (int j = 0; j < 4; ++j)
        outF[(size_t)(nb + j) * 256 + gc] = acc[ct][j] + bv;
    }
  }
}

// ---------------- finalize: combined Q-side scale c = temp*log2e/(|q||k|) ----
__global__ __launch_bounds__(512) void k_norm2(
    const float* __restrict__ partQ, const float* __restrict__ partK,
    const float* __restrict__ temp, f16* __restrict__ cqh)
{
  const int t = threadIdx.x;            // 512 = 8 bh * 64 dd
  const int bh = t >> 6, dd = t & 63;
  float sq = 0.f, sk = 0.f;
  for (int s = 0; s < 64; ++s) {
    sq += partQ[(bh * 64 + s) * 64 + dd];
    sk += partK[(bh * 64 + s) * 64 + dd];
  }
  float c = temp[bh & 3] * 1.4426950408889634f /
            (fmaxf(sqrtf(sq), 1e-12f) * fmaxf(sqrtf(sk), 1e-12f));
  cqh[t] = (f16)c;
}

// ---------------- flash attention v4: QBLK=128, unique wave tiles, 2-phase dbuf
// 8 waves = (ks 0..3 key-slice) x (qh 0..1 query-half).  32 stages of 128-key
// tiles, double-buffered 2x32KB LDS via global_load_lds (linear dest, source
// pre-swizzled, XOR-swizzled reads).  Per wave: 32 keys x 64 queries (2 sets).
__device__ inline void plane_swap(u32& a, u32& b) {
  asm volatile("v_permlane32_swap_b32 %0, %1" : "+v"(a), "+v"(b));
}

__global__ __launch_bounds__(512, 2) void k_flash4(
    const f16* __restrict__ Qb, const f16* __restrict__ Kb,
    const f16* __restrict__ Vtb, const f16* __restrict__ cqh,
    f16* __restrict__ Y)
{
  __shared__ f16 KVl[32768];    // 2 x (K 128x64 | V 64x128) = 64KB; aliased by epilogue
  __shared__ float Lsh[512];    // [w][64 q] row sums
  const int t = threadIdx.x, w = t >> 6, l = t & 63;
  const int r = l & 31, hi = l >> 5;
  const int ks = w >> 1, qh = w & 1;
  const int r7 = r & 7;
  // XCD-bijective swizzle: 256 blocks, each XCD owns one (b,h)
  int nb2 = (blockIdx.x & 7) * 32 + (blockIdx.x >> 3);
  const int bh = nb2 >> 5, qt = nb2 & 31;
  const size_t base = (size_t)bh * NTOK * 64;
  // Q fragments: 2 sets x 4 chunks, scaled by combined per-d factor c
  f16x8 qf[2][4];
  {
    const f16* cp = cqh + bh * 64;
#pragma unroll
    for (int s = 0; s < 2; ++s) {
      const f16* qp = Qb + base + (size_t)(qt * 128 + qh * 64 + s * 32 + r) * 64 + hi * 8;
#pragma unroll
      for (int c = 0; c < 4; ++c)
        qf[s][c] = *(const f16x8*)(qp + c * 16) * *(const f16x8*)(cp + c * 16 + hi * 8);
    }
  }
  // staging source pointers (pre-swizzled global addresses, rule #21)
  const f16* srcK = Kb + base + (size_t)(w * 8 + (l >> 3)) * 64 + ((l & 7) ^ (l >> 3)) * 8;
  const int vrow = w * 4 + (l >> 4);
  const f16* srcV = Vtb + base + (size_t)vrow * 4096 + ((l & 15) ^ (vrow & 7)) * 8;
  const int dK = w * 8 * 64;            // + j*4096 + cur*16384
  const int dV = 8192 + w * 4 * 128;
#define STAGE(cur, tile) { \
    const f16* sk_ = srcK + (size_t)(tile) * 8192; \
    const f16* sv_ = srcV + (tile) * 128; \
    GLL(sk_,          KVl + (cur) * 16384 + dK); \
    GLL(sk_ + 4096,   KVl + (cur) * 16384 + dK + 4096); \
    GLL(sv_,          KVl + (cur) * 16384 + dV); \
    GLL(sv_ + 131072, KVl + (cur) * 16384 + dV + 4096); }
  // fragment read offsets (f16 units, constant across stages)
  const int kro = (ks * 32 + r) * 64;
  const int kc0 = ((0 + hi) ^ r7) * 8, kc1 = ((2 + hi) ^ r7) * 8;
  const int kc2 = ((4 + hi) ^ r7) * 8, kc3 = ((6 + hi) ^ r7) * 8;
  const int vb0 = 8192 + r * 128, vb1 = 8192 + (32 + r) * 128;
  const int vc0 = ((ks * 4 + 0 + hi) ^ r7) * 8, vc1 = ((ks * 4 + 2 + hi) ^ r7) * 8;

  f32x16 oacc[2][2] = {};
  float ls[2] = {0.f, 0.f};
  STAGE(0, 0);
  __syncthreads();
  for (int tl = 0; tl < 32; ++tl) {
    const int cur = tl & 1;
    if (tl < 31) STAGE(cur ^ 1, tl + 1);
    const f16* B = KVl + cur * 16384;
    f16x8 kf0 = *(const f16x8*)(B + kro + kc0);
    f16x8 kf1 = *(const f16x8*)(B + kro + kc1);
    f16x8 kf2 = *(const f16x8*)(B + kro + kc2);
    f16x8 kf3 = *(const f16x8*)(B + kro + kc3);
    f16x8 vf00 = *(const f16x8*)(B + vb0 + vc0);
    f16x8 vf01 = *(const f16x8*)(B + vb0 + vc1);
    f16x8 vf10 = *(const f16x8*)(B + vb1 + vc0);
    f16x8 vf11 = *(const f16x8*)(B + vb1 + vc1);
#pragma unroll
    for (int s = 0; s < 2; ++s) {
      f32x16 sacc = {};
      sacc = __builtin_amdgcn_mfma_f32_32x32x16_f16(kf0, qf[s][0], sacc, 0, 0, 0);
      sacc = __builtin_amdgcn_mfma_f32_32x32x16_f16(kf1, qf[s][1], sacc, 0, 0, 0);
      sacc = __builtin_amdgcn_mfma_f32_32x32x16_f16(kf2, qf[s][2], sacc, 0, 0, 0);
      sacc = __builtin_amdgcn_mfma_f32_32x32x16_f16(kf3, qf[s][3], sacc, 0, 0, 0);
      u32 Dw[8];
#pragma unroll
      for (int u = 0; u < 4; ++u) {
#pragma unroll
        for (int v = 0; v < 2; ++v) {
          float a  = exp2f(sacc[u * 4 + v * 2]);
          float b2 = exp2f(sacc[u * 4 + v * 2 + 1]);
          ls[s] += a + b2;
          union { fp16x2 h; u32 u; } cv;
          cv.h = __builtin_amdgcn_cvt_pkrtz(a, b2);
          Dw[u * 2 + v] = cv.u;
        }
      }
      plane_swap(Dw[0], Dw[2]);
      plane_swap(Dw[1], Dw[3]);
      plane_swap(Dw[4], Dw[6]);
      plane_swap(Dw[5], Dw[7]);
      union { f16x8 v; u32 d[4]; } p0, p1;
      p0.d[0] = Dw[0]; p0.d[1] = Dw[1]; p0.d[2] = Dw[2]; p0.d[3] = Dw[3];
      p1.d[0] = Dw[4]; p1.d[1] = Dw[5]; p1.d[2] = Dw[6]; p1.d[3] = Dw[7];
      oacc[s][0] = __builtin_amdgcn_mfma_f32_32x32x16_f16(p0.v, vf00, oacc[s][0], 0, 0, 0);
      oacc[s][0] = __builtin_amdgcn_mfma_f32_32x32x16_f16(p1.v, vf01, oacc[s][0], 0, 0, 0);
      oacc[s][1] = __builtin_amdgcn_mfma_f32_32x32x16_f16(p0.v, vf10, oacc[s][1], 0, 0, 0);
      oacc[s][1] = __builtin_amdgcn_mfma_f32_32x32x16_f16(p1.v, vf11, oacc[s][1], 0, 0, 0);
    }
    __syncthreads();
  }
#undef STAGE
  // ---- epilogue: combine 4 key-slice partials via LDS ----
  ls[0] += __shfl_xor(ls[0], 32, 64);
  ls[1] += __shfl_xor(ls[1], 32, 64);
  if (hi == 0) { Lsh[w * 64 + r] = ls[0]; Lsh[w * 64 + 32 + r] = ls[1]; }
  // spill oacc as f16 into (now free) staging LDS: [w][dd 0..63][q-chunk^swz][8]
#pragma unroll
  for (int s = 0; s < 2; ++s)
#pragma unroll
    for (int dt = 0; dt < 2; ++dt) {
      f16* orow = KVl + w * 4096 + (dt * 32 + r) * 64;
      const f32x16& oa = oacc[s][dt];
#pragma unroll
      for (int u = 0; u < 4; ++u) {
        f16x4 h4;
        h4[0] = (f16)oa[u * 4 + 0]; h4[1] = (f16)oa[u * 4 + 1];
        h4[2] = (f16)oa[u * 4 + 2]; h4[3] = (f16)oa[u * 4 + 3];
        *(f16x4*)(orow + (((s * 4 + u) ^ r7) * 8) + hi * 4) = h4;
      }
    }
  __syncthreads();
  // combine region (s2, dt2, qh2) <- wave w; sum 4 key-slices
  const int s2 = w >> 2, dt2 = (w >> 1) & 1, qh2 = w & 1;
  const int b = bh >> 2, h = bh & 3;
#pragma unroll
  for (int c = 0; c < 2; ++c) {
    float accv[8] = {}, denv[8] = {};
#pragma unroll
    for (int ksl = 0; ksl < 4; ++ksl) {
      const int wp = ksl * 2 + qh2;
      f16x8 rd = *(const f16x8*)(KVl + wp * 4096 + (dt2 * 32 + r) * 64 +
                                 (((s2 * 4 + hi * 2 + c) ^ r7) * 8));
      f32x4 la = *(const f32x4*)(Lsh + wp * 64 + s2 * 32 + hi * 16 + c * 8);
      f32x4 lb = *(const f32x4*)(Lsh + wp * 64 + s2 * 32 + hi * 16 + c * 8 + 4);
#pragma unroll
      for (int j = 0; j < 4; ++j) {
        accv[j]     += (float)rd[j];
        accv[4 + j] += (float)rd[4 + j];
        denv[j]     += la[j];
        denv[4 + j] += lb[j];
      }
    }
    const int ng = qt * 128 + qh2 * 64 + s2 * 32 + hi * 16 + c * 8;
    const int np = (dt2 * 32 + r) * 64 + h * 16 + (ng >> 8);
    const int cp_ = ng & 255;
    f16x8 yv;
#pragma unroll
    for (int j = 0; j < 8; ++j) yv[j] = (f16)(accv[j] / denv[j]);
    *(f16x8*)(Y + ((size_t)b * 4096 + np) * 256 + cp_) = yv;
  }
}

extern "C" void kernel_launch(void* const* d_in, const int* in_sizes, int n_in,
                              void* d_out, int out_size, void* d_ws, size_t ws_size,
                              hipStream_t stream)
{
  const float* x     = (const float*)d_in[0];   // [2,4096,256]
  const float* w_qkv = (const float*)d_in[1];   // [768,256]
  const float* w_out = (const float*)d_in[2];   // [256,256]
  const float* b_out = (const float*)d_in[3];   // [256]
  const float* temp  = (const float*)d_in[4];   // [4,1,1]

  char* ws = (char*)d_ws;
  f16*   xb    = (f16*)(ws);                                  // 4MB
  f16*   wqkvb = (f16*)(ws + 4 * 1024 * 1024);
  f16*   woutb = (f16*)(ws + 4 * 1024 * 1024 + 512 * 1024);
  f16*   Qb    = (f16*)(ws + 5  * 1024 * 1024);               // [8][4096][64]
  f16*   Kb    = (f16*)(ws + 9  * 1024 * 1024);
  f16*   Vtb   = (f16*)(ws + 13 * 1024 * 1024);               // [8][64][4096]
  f16*   cqh   = (f16*)(ws + 17 * 1024 * 1024);               // 512 f16
  float* partQ = (float*)(ws + 17 * 1024 * 1024 + 8192);      // 128KB
  float* partK = (float*)(ws + 17 * 1024 * 1024 + 8192 + 131072);
  f16*   Y     = (f16*)(ws + 18 * 1024 * 1024);               // [2][4096][256]
  float* outF  = (float*)d_out;

  k_cvt<<<2304, 256, 0, stream>>>(x, w_qkv, w_out, xb, wqkvb, woutb);
  k_gemm<<<dim3(12, 128), 256, 0, stream>>>(xb, wqkvb, 256, 0, Qb, Kb, Vtb,
                                            nullptr, nullptr, partQ, partK);
  k_norm2<<<1, 512, 0, stream>>>(partQ, partK, temp, cqh);
  k_flash4<<<256, 512, 0, stream>>>(Qb, Kb, Vtb, cqh, Y);
  k_gemm<<<dim3(4, 128), 256, 0, stream>>>(Y, woutb, 256, 1, nullptr, nullptr, nullptr,
                                           outF, b_out, nullptr, nullptr);
}

// Round 8
// 88.589 us; speedup vs baseline: 2.1198x; 1.0925x over previous
//
#include <hip/hip_runtime.h>

typedef _Float16 f16;
typedef f16 f16x8 __attribute__((ext_vector_type(8)));
typedef f16 f16x4 __attribute__((ext_vector_type(4)));
typedef __fp16 fp16x2 __attribute__((ext_vector_type(2)));
typedef float f32x4 __attribute__((ext_vector_type(4)));
typedef float f32x16 __attribute__((ext_vector_type(16)));
typedef unsigned int u32;

#define NTOK 4096

// async global->LDS, 16B per lane; dest = wave-uniform base + lane*16
#define GLL(gsrc, ldst) \
  __builtin_amdgcn_global_load_lds( \
      (const __attribute__((address_space(1))) void*)(gsrc), \
      (__attribute__((address_space(3))) void*)(ldst), 16, 0, 0)

// ---------------- fused f32 -> f16 convert (x | w_qkv | w_out) ----------------
__global__ __launch_bounds__(256) void k_cvt(
    const float* __restrict__ x, const float* __restrict__ wq,
    const float* __restrict__ wo,
    f16* __restrict__ xb, f16* __restrict__ wqb, f16* __restrict__ wob)
{
  const int bx = blockIdx.x;
  const float* src; f16* dst; int off;
  if (bx < 2048)      { src = x;  dst = xb;  off = bx * 1024; }
  else if (bx < 2240) { src = wq; dst = wqb; off = (bx - 2048) * 1024; }
  else                { src = wo; dst = wob; off = (bx - 2240) * 1024; }
  const int i = off + threadIdx.x * 4;
  float4 f = *(const float4*)(src + i);
  f16x4 h;
  h[0] = (f16)f.x; h[1] = (f16)f.y; h[2] = (f16)f.z; h[3] = (f16)f.w;
  *(f16x4*)(dst + i) = h;
}

// ---------------- generic C = A[M,K] * W[NC,K]^T MFMA GEMM ----------------
// mode 0: QKV epilogue -> scatter to Qb/Kb/Vtb + fused norm partial sums (f32 acc)
// mode 1: out epilogue -> d_out f32 + bias
__global__ __launch_bounds__(256) void k_gemm(
    const f16* __restrict__ A, const f16* __restrict__ W,
    int K, int mode,
    f16* __restrict__ Qb, f16* __restrict__ Kb, f16* __restrict__ Vtb,
    float* __restrict__ outF, const float* __restrict__ bias,
    float* __restrict__ partQ, float* __restrict__ partK)
{
  __shared__ f16 Al[64 * 40];
  __shared__ f16 Wl[64 * 40];
  __shared__ float redl[4][64];
  const int t = threadIdx.x;
  const int w = t >> 6, l = t & 63;
  const int lrow = l & 15, lk = l >> 4;
  const int m0 = blockIdx.y * 64, nc0 = blockIdx.x * 64;
  f32x4 acc[4] = {};
  const int srow = t >> 2, sseg = t & 3;
  for (int k0 = 0; k0 < K; k0 += 32) {
    __syncthreads();
    f16x8 av = *(const f16x8*)(A + (size_t)(m0 + srow) * K + k0 + sseg * 8);
    f16x8 wv = *(const f16x8*)(W + (size_t)(nc0 + srow) * K + k0 + sseg * 8);
    *(f16x8*)(Al + srow * 40 + sseg * 8) = av;
    *(f16x8*)(Wl + srow * 40 + sseg * 8) = wv;
    __syncthreads();
    f16x8 af = *(const f16x8*)(Al + (w * 16 + lrow) * 40 + lk * 8);
#pragma unroll
    for (int ct = 0; ct < 4; ++ct) {
      f16x8 bf = *(const f16x8*)(Wl + (ct * 16 + lrow) * 40 + lk * 8);
      acc[ct] = __builtin_amdgcn_mfma_f32_16x16x32_f16(af, bf, acc[ct], 0, 0, 0);
    }
  }
  const int nb = m0 + w * 16 + lk * 4;
  if (mode == 0) {
    const int b = nb >> 12, n = nb & 4095;
#pragma unroll
    for (int ct = 0; ct < 4; ++ct) {
      int gc = nc0 + ct * 16 + lrow;
      int s = gc >> 8, h = (gc >> 6) & 3, dd = gc & 63;
      int bh = b * 4 + h;
      if (s == 2) {
        f16x4 v;
#pragma unroll
        for (int j = 0; j < 4; ++j) v[j] = (f16)acc[ct][j];
        *(f16x4*)(Vtb + ((size_t)bh * 64 + dd) * 4096 + n) = v;
      } else {
        f16* dst = (s == 0) ? Qb : Kb;
#pragma unroll
        for (int j = 0; j < 4; ++j)
          dst[((size_t)bh * 4096 + n + j) * 64 + dd] = (f16)acc[ct][j];
      }
    }
    // fused per-channel squared-sum partials (over this block's 64 tokens)
    if (nc0 < 512) {
#pragma unroll
      for (int ct = 0; ct < 4; ++ct) {
        float v = acc[ct][0] * acc[ct][0] + acc[ct][1] * acc[ct][1]
                + acc[ct][2] * acc[ct][2] + acc[ct][3] * acc[ct][3];
        v += __shfl_xor(v, 16, 64);
        v += __shfl_xor(v, 32, 64);
        if (lk == 0) redl[w][ct * 16 + lrow] = v;
      }
      __syncthreads();
      if (t < 64) {
        float sq = redl[0][t] + redl[1][t] + redl[2][t] + redl[3][t];
        const int s = nc0 >> 8, h2 = (nc0 >> 6) & 3;
        const int b2 = m0 >> 12, mb = (m0 >> 6) & 63;
        float* dst = (s == 0) ? partQ : partK;
        dst[((b2 * 4 + h2) * 64 + mb) * 64 + t] = sq;
      }
    }
  } else {
#pragma unroll
    for (int ct = 0; ct < 4; ++ct) {
      int gc = nc0 + ct * 16 + lrow;
      float bv = bias[gc];
#pragma unroll
      for (int j = 0; j < 4; ++j)
        outF[(size_t)(nb + j) * 256 + gc] = acc[ct][j] + bv;
    }
  }
}

// ---------------- finalize: combined Q-side scale c = temp*log2e/(|q||k|) ----
__global__ __launch_bounds__(512) void k_norm2(
    const float* __restrict__ partQ, const float* __restrict__ partK,
    const float* __restrict__ temp, f16* __restrict__ cqh)
{
  const int t = threadIdx.x;            // 512 = 8 bh * 64 dd
  const int bh = t >> 6, dd = t & 63;
  float sq = 0.f, sk = 0.f;
  for (int s = 0; s < 64; ++s) {
    sq += partQ[(bh * 64 + s) * 64 + dd];
    sk += partK[(bh * 64 + s) * 64 + dd];
  }
  float c = temp[bh & 3] * 1.4426950408889634f /
            (fmaxf(sqrtf(sq), 1e-12f) * fmaxf(sqrtf(sk), 1e-12f));
  cqh[t] = (f16)c;
}

// ---------------- flash attention v5: T15 2-deep pipeline + T5 setprio --------
// flash4 structure (QBLK=128, 8 waves = 4 ks x 2 qh, 2-phase GLL dbuf) with the
// inner loop software-pipelined: QK(cur) MFMAs overlap softmax(prev) VALU;
// V-fragments carried in registers so PV(prev) survives buffer overwrite.
__device__ inline void plane_swap(u32& a, u32& b) {
  asm volatile("v_permlane32_swap_b32 %0, %1" : "+v"(a), "+v"(b));
}

__global__ __launch_bounds__(512, 2) void k_flash5(
    const f16* __restrict__ Qb, const f16* __restrict__ Kb,
    const f16* __restrict__ Vtb, const f16* __restrict__ cqh,
    f16* __restrict__ Y)
{
  __shared__ f16 KVl[32768];    // 2 x (K 128x64 | V 64x128) = 64KB; aliased by epilogue
  __shared__ float Lsh[512];    // [w][64 q] row sums
  const int t = threadIdx.x, w = t >> 6, l = t & 63;
  const int r = l & 31, hi = l >> 5;
  const int ks = w >> 1, qh = w & 1;
  const int r7 = r & 7;
  // XCD-bijective swizzle: 256 blocks, each XCD owns one (b,h)
  int nb2 = (blockIdx.x & 7) * 32 + (blockIdx.x >> 3);
  const int bh = nb2 >> 5, qt = nb2 & 31;
  const size_t base = (size_t)bh * NTOK * 64;
  // Q fragments: 2 sets x 4 chunks, scaled by combined per-d factor c
  f16x8 qf[2][4];
  {
    const f16* cp = cqh + bh * 64;
#pragma unroll
    for (int s = 0; s < 2; ++s) {
      const f16* qp = Qb + base + (size_t)(qt * 128 + qh * 64 + s * 32 + r) * 64 + hi * 8;
#pragma unroll
      for (int c = 0; c < 4; ++c)
        qf[s][c] = *(const f16x8*)(qp + c * 16) * *(const f16x8*)(cp + c * 16 + hi * 8);
    }
  }
  // staging source pointers (pre-swizzled global addresses, rule #21)
  const f16* srcK = Kb + base + (size_t)(w * 8 + (l >> 3)) * 64 + ((l & 7) ^ (l >> 3)) * 8;
  const int vrow = w * 4 + (l >> 4);
  const f16* srcV = Vtb + base + (size_t)vrow * 4096 + ((l & 15) ^ (vrow & 7)) * 8;
  const int dK = w * 8 * 64;
  const int dV = 8192 + w * 4 * 128;
#define STAGE(cur, tile) { \
    const f16* sk_ = srcK + (size_t)(tile) * 8192; \
    const f16* sv_ = srcV + (tile) * 128; \
    GLL(sk_,          KVl + (cur) * 16384 + dK); \
    GLL(sk_ + 4096,   KVl + (cur) * 16384 + dK + 4096); \
    GLL(sv_,          KVl + (cur) * 16384 + dV); \
    GLL(sv_ + 131072, KVl + (cur) * 16384 + dV + 4096); }
  // fragment read offsets (f16 units, constant across stages)
  const int kro = (ks * 32 + r) * 64;
  const int kc0 = ((0 + hi) ^ r7) * 8, kc1 = ((2 + hi) ^ r7) * 8;
  const int kc2 = ((4 + hi) ^ r7) * 8, kc3 = ((6 + hi) ^ r7) * 8;
  const int vb0 = 8192 + r * 128, vb1 = 8192 + (32 + r) * 128;
  const int vc0 = ((ks * 4 + 0 + hi) ^ r7) * 8, vc1 = ((ks * 4 + 2 + hi) ^ r7) * 8;

// QK into named sacc (static set index)
#define QKSTEP(SACC, QS) { \
    SACC = (f32x16){}; \
    SACC = __builtin_amdgcn_mfma_f32_32x32x16_f16(kf0, qf[QS][0], SACC, 0, 0, 0); \
    SACC = __builtin_amdgcn_mfma_f32_32x32x16_f16(kf1, qf[QS][1], SACC, 0, 0, 0); \
    SACC = __builtin_amdgcn_mfma_f32_32x32x16_f16(kf2, qf[QS][2], SACC, 0, 0, 0); \
    SACC = __builtin_amdgcn_mfma_f32_32x32x16_f16(kf3, qf[QS][3], SACC, 0, 0, 0); }

// softmax(SACC) + PV into oacc[OIDX] using named V fragments (all static)
#define SMPV(SACC, LS, OIDX, V0, V1, V2, V3) { \
    u32 Dw[8]; \
    _Pragma("unroll") \
    for (int u = 0; u < 4; ++u) { \
      _Pragma("unroll") \
      for (int v = 0; v < 2; ++v) { \
        float a  = exp2f(SACC[u * 4 + v * 2]); \
        float b2 = exp2f(SACC[u * 4 + v * 2 + 1]); \
        LS += a + b2; \
        union { fp16x2 h; u32 u; } cv; \
        cv.h = __builtin_amdgcn_cvt_pkrtz(a, b2); \
        Dw[u * 2 + v] = cv.u; \
      } \
    } \
    plane_swap(Dw[0], Dw[2]); \
    plane_swap(Dw[1], Dw[3]); \
    plane_swap(Dw[4], Dw[6]); \
    plane_swap(Dw[5], Dw[7]); \
    union { f16x8 v; u32 d[4]; } p0, p1; \
    p0.d[0] = Dw[0]; p0.d[1] = Dw[1]; p0.d[2] = Dw[2]; p0.d[3] = Dw[3]; \
    p1.d[0] = Dw[4]; p1.d[1] = Dw[5]; p1.d[2] = Dw[6]; p1.d[3] = Dw[7]; \
    __builtin_amdgcn_s_setprio(1); \
    oacc[OIDX][0] = __builtin_amdgcn_mfma_f32_32x32x16_f16(p0.v, V0, oacc[OIDX][0], 0, 0, 0); \
    oacc[OIDX][0] = __builtin_amdgcn_mfma_f32_32x32x16_f16(p1.v, V1, oacc[OIDX][0], 0, 0, 0); \
    oacc[OIDX][1] = __builtin_amdgcn_mfma_f32_32x32x16_f16(p0.v, V2, oacc[OIDX][1], 0, 0, 0); \
    oacc[OIDX][1] = __builtin_amdgcn_mfma_f32_32x32x16_f16(p1.v, V3, oacc[OIDX][1], 0, 0, 0); \
    __builtin_amdgcn_s_setprio(0); }

  f32x16 oacc[2][2] = {};
  f32x16 saccA = {}, saccB = {};
  float ls0 = 0.f, ls1 = 0.f;
  f16x8 vfp0 = {}, vfp1 = {}, vfp2 = {}, vfp3 = {};
  STAGE(0, 0);
  __syncthreads();
  for (int tl = 0; tl < 32; ++tl) {
    const int cur = tl & 1;
    const f16* Bb = KVl + cur * 16384;
    f16x8 kf0 = *(const f16x8*)(Bb + kro + kc0);
    f16x8 kf1 = *(const f16x8*)(Bb + kro + kc1);
    f16x8 kf2 = *(const f16x8*)(Bb + kro + kc2);
    f16x8 kf3 = *(const f16x8*)(Bb + kro + kc3);
    f16x8 vfc0 = *(const f16x8*)(Bb + vb0 + vc0);
    f16x8 vfc1 = *(const f16x8*)(Bb + vb0 + vc1);
    f16x8 vfc2 = *(const f16x8*)(Bb + vb1 + vc0);
    f16x8 vfc3 = *(const f16x8*)(Bb + vb1 + vc1);
    if (tl < 31) STAGE(cur ^ 1, tl + 1);
    // step A: QK(set0) MFMAs; softmax+PV of previous step fills their shadow
    __builtin_amdgcn_s_setprio(1);
    QKSTEP(saccA, 0);
    __builtin_amdgcn_s_setprio(0);
    if (tl > 0) SMPV(saccB, ls1, 1, vfp0, vfp1, vfp2, vfp3);
    // step B: QK(set1) MFMAs; softmax+PV(set0, this tile) in their shadow
    __builtin_amdgcn_s_setprio(1);
    QKSTEP(saccB, 1);
    __builtin_amdgcn_s_setprio(0);
    SMPV(saccA, ls0, 0, vfc0, vfc1, vfc2, vfc3);
    vfp0 = vfc0; vfp1 = vfc1; vfp2 = vfc2; vfp3 = vfc3;
    __syncthreads();
  }
  // drain the pipeline: last set-1 tile
  SMPV(saccB, ls1, 1, vfp0, vfp1, vfp2, vfp3);
#undef STAGE
#undef QKSTEP
#undef SMPV
  // ---- epilogue: combine 4 key-slice partials via LDS ----
  ls0 += __shfl_xor(ls0, 32, 64);
  ls1 += __shfl_xor(ls1, 32, 64);
  if (hi == 0) { Lsh[w * 64 + r] = ls0; Lsh[w * 64 + 32 + r] = ls1; }
  // spill oacc as f16 into (now free) staging LDS: [w][dd 0..63][q-chunk^swz][8]
#pragma unroll
  for (int s = 0; s < 2; ++s)
#pragma unroll
    for (int dt = 0; dt < 2; ++dt) {
      f16* orow = KVl + w * 4096 + (dt * 32 + r) * 64;
      const f32x16& oa = oacc[s][dt];
#pragma unroll
      for (int u = 0; u < 4; ++u) {
        f16x4 h4;
        h4[0] = (f16)oa[u * 4 + 0]; h4[1] = (f16)oa[u * 4 + 1];
        h4[2] = (f16)oa[u * 4 + 2]; h4[3] = (f16)oa[u * 4 + 3];
        *(f16x4*)(orow + (((s * 4 + u) ^ r7) * 8) + hi * 4) = h4;
      }
    }
  __syncthreads();
  // combine region (s2, dt2, qh2) <- wave w; sum 4 key-slices
  const int s2 = w >> 2, dt2 = (w >> 1) & 1, qh2 = w & 1;
  const int b = bh >> 2, h = bh & 3;
#pragma unroll
  for (int c = 0; c < 2; ++c) {
    float accv[8] = {}, denv[8] = {};
#pragma unroll
    for (int ksl = 0; ksl < 4; ++ksl) {
      const int wp = ksl * 2 + qh2;
      f16x8 rd = *(const f16x8*)(KVl + wp * 4096 + (dt2 * 32 + r) * 64 +
                                 (((s2 * 4 + hi * 2 + c) ^ r7) * 8));
      f32x4 la = *(const f32x4*)(Lsh + wp * 64 + s2 * 32 + hi * 16 + c * 8);
      f32x4 lb = *(const f32x4*)(Lsh + wp * 64 + s2 * 32 + hi * 16 + c * 8 + 4);
#pragma unroll
      for (int j = 0; j < 4; ++j) {
        accv[j]     += (float)rd[j];
        accv[4 + j] += (float)rd[4 + j];
        denv[j]     += la[j];
        denv[4 + j] += lb[j];
      }
    }
    const int ng = qt * 128 + qh2 * 64 + s2 * 32 + hi * 16 + c * 8;
    const int np = (dt2 * 32 + r) * 64 + h * 16 + (ng >> 8);
    const int cp_ = ng & 255;
    f16x8 yv;
#pragma unroll
    for (int j = 0; j < 8; ++j) yv[j] = (f16)(accv[j] / denv[j]);
    *(f16x8*)(Y + ((size_t)b * 4096 + np) * 256 + cp_) = yv;
  }
}

extern "C" void kernel_launch(void* const* d_in, const int* in_sizes, int n_in,
                              void* d_out, int out_size, void* d_ws, size_t ws_size,
                              hipStream_t stream)
{
  const float* x     = (const float*)d_in[0];   // [2,4096,256]
  const float* w_qkv = (const float*)d_in[1];   // [768,256]
  const float* w_out = (const float*)d_in[2];   // [256,256]
  const float* b_out = (const float*)d_in[3];   // [256]
  const float* temp  = (const float*)d_in[4];   // [4,1,1]

  char* ws = (char*)d_ws;
  f16*   xb    = (f16*)(ws);                                  // 4MB
  f16*   wqkvb = (f16*)(ws + 4 * 1024 * 1024);
  f16*   woutb = (f16*)(ws + 4 * 1024 * 1024 + 512 * 1024);
  f16*   Qb    = (f16*)(ws + 5  * 1024 * 1024);               // [8][4096][64]
  f16*   Kb    = (f16*)(ws + 9  * 1024 * 1024);
  f16*   Vtb   = (f16*)(ws + 13 * 1024 * 1024);               // [8][64][4096]
  f16*   cqh   = (f16*)(ws + 17 * 1024 * 1024);               // 512 f16
  float* partQ = (float*)(ws + 17 * 1024 * 1024 + 8192);      // 128KB
  float* partK = (float*)(ws + 17 * 1024 * 1024 + 8192 + 131072);
  f16*   Y     = (f16*)(ws + 18 * 1024 * 1024);               // [2][4096][256]
  float* outF  = (float*)d_out;

  k_cvt<<<2304, 256, 0, stream>>>(x, w_qkv, w_out, xb, wqkvb, woutb);
  k_gemm<<<dim3(12, 128), 256, 0, stream>>>(xb, wqkvb, 256, 0, Qb, Kb, Vtb,
                                            nullptr, nullptr, partQ, partK);
  k_norm2<<<1, 512, 0, stream>>>(partQ, partK, temp, cqh);
  k_flash5<<<256, 512, 0, stream>>>(Qb, Kb, Vtb, cqh, Y);
  k_gemm<<<dim3(4, 128), 256, 0, stream>>>(Y, woutb, 256, 1, nullptr, nullptr, nullptr,
                                           outF, b_out, nullptr, nullptr);
}

// Round 9
// 83.268 us; speedup vs baseline: 2.2552x; 1.0639x over previous
//
#include <hip/hip_runtime.h>

typedef _Float16 f16;
typedef f16 f16x8 __attribute__((ext_vector_type(8)));
typedef f16 f16x4 __attribute__((ext_vector_type(4)));
typedef __fp16 fp16x2 __attribute__((ext_vector_type(2)));
typedef float f32x4 __attribute__((ext_vector_type(4)));
typedef float f32x16 __attribute__((ext_vector_type(16)));
typedef unsigned int u32;

#define NTOK 4096

// async global->LDS, 16B per lane; dest = wave-uniform base + lane*16
#define GLL(gsrc, ldst) \
  __builtin_amdgcn_global_load_lds( \
      (const __attribute__((address_space(1))) void*)(gsrc), \
      (__attribute__((address_space(3))) void*)(ldst), 16, 0, 0)

// ---------------- fused f32 -> f16 convert (x | w_qkv | w_out) ----------------
__global__ __launch_bounds__(256) void k_cvt(
    const float* __restrict__ x, const float* __restrict__ wq,
    const float* __restrict__ wo,
    f16* __restrict__ xb, f16* __restrict__ wqb, f16* __restrict__ wob)
{
  const int bx = blockIdx.x;
  const float* src; f16* dst; int off;
  if (bx < 2048)      { src = x;  dst = xb;  off = bx * 1024; }
  else if (bx < 2240) { src = wq; dst = wqb; off = (bx - 2048) * 1024; }
  else                { src = wo; dst = wob; off = (bx - 2240) * 1024; }
  const int i = off + threadIdx.x * 4;
  float4 f = *(const float4*)(src + i);
  f16x4 h;
  h[0] = (f16)f.x; h[1] = (f16)f.y; h[2] = (f16)f.z; h[3] = (f16)f.w;
  *(f16x4*)(dst + i) = h;
}

// ---------------- generic C = A[M,K] * W[NC,K]^T MFMA GEMM ----------------
// mode 0: QKV epilogue -> scatter to Qb/Kb/Vtb + fused norm partial sums (f32 acc)
// mode 1: out epilogue -> d_out f32 + bias
__global__ __launch_bounds__(256) void k_gemm(
    const f16* __restrict__ A, const f16* __restrict__ W,
    int K, int mode,
    f16* __restrict__ Qb, f16* __restrict__ Kb, f16* __restrict__ Vtb,
    float* __restrict__ outF, const float* __restrict__ bias,
    float* __restrict__ partQ, float* __restrict__ partK)
{
  __shared__ f16 Al[64 * 40];
  __shared__ f16 Wl[64 * 40];
  __shared__ float redl[4][64];
  const int t = threadIdx.x;
  const int w = t >> 6, l = t & 63;
  const int lrow = l & 15, lk = l >> 4;
  const int m0 = blockIdx.y * 64, nc0 = blockIdx.x * 64;
  f32x4 acc[4] = {};
  const int srow = t >> 2, sseg = t & 3;
  for (int k0 = 0; k0 < K; k0 += 32) {
    __syncthreads();
    f16x8 av = *(const f16x8*)(A + (size_t)(m0 + srow) * K + k0 + sseg * 8);
    f16x8 wv = *(const f16x8*)(W + (size_t)(nc0 + srow) * K + k0 + sseg * 8);
    *(f16x8*)(Al + srow * 40 + sseg * 8) = av;
    *(f16x8*)(Wl + srow * 40 + sseg * 8) = wv;
    __syncthreads();
    f16x8 af = *(const f16x8*)(Al + (w * 16 + lrow) * 40 + lk * 8);
#pragma unroll
    for (int ct = 0; ct < 4; ++ct) {
      f16x8 bf = *(const f16x8*)(Wl + (ct * 16 + lrow) * 40 + lk * 8);
      acc[ct] = __builtin_amdgcn_mfma_f32_16x16x32_f16(af, bf, acc[ct], 0, 0, 0);
    }
  }
  const int nb = m0 + w * 16 + lk * 4;
  if (mode == 0) {
    const int b = nb >> 12, n = nb & 4095;
#pragma unroll
    for (int ct = 0; ct < 4; ++ct) {
      int gc = nc0 + ct * 16 + lrow;
      int s = gc >> 8, h = (gc >> 6) & 3, dd = gc & 63;
      int bh = b * 4 + h;
      if (s == 2) {
        f16x4 v;
#pragma unroll
        for (int j = 0; j < 4; ++j) v[j] = (f16)acc[ct][j];
        *(f16x4*)(Vtb + ((size_t)bh * 64 + dd) * 4096 + n) = v;
      } else {
        f16* dst = (s == 0) ? Qb : Kb;
#pragma unroll
        for (int j = 0; j < 4; ++j)
          dst[((size_t)bh * 4096 + n + j) * 64 + dd] = (f16)acc[ct][j];
      }
    }
    // fused per-channel squared-sum partials (over this block's 64 tokens)
    if (nc0 < 512) {
#pragma unroll
      for (int ct = 0; ct < 4; ++ct) {
        float v = acc[ct][0] * acc[ct][0] + acc[ct][1] * acc[ct][1]
                + acc[ct][2] * acc[ct][2] + acc[ct][3] * acc[ct][3];
        v += __shfl_xor(v, 16, 64);
        v += __shfl_xor(v, 32, 64);
        if (lk == 0) redl[w][ct * 16 + lrow] = v;
      }
      __syncthreads();
      if (t < 64) {
        float sq = redl[0][t] + redl[1][t] + redl[2][t] + redl[3][t];
        const int s = nc0 >> 8, h2 = (nc0 >> 6) & 3;
        const int b2 = m0 >> 12, mb = (m0 >> 6) & 63;
        float* dst = (s == 0) ? partQ : partK;
        dst[((b2 * 4 + h2) * 64 + mb) * 64 + t] = sq;
      }
    }
  } else {
#pragma unroll
    for (int ct = 0; ct < 4; ++ct) {
      int gc = nc0 + ct * 16 + lrow;
      float bv = bias[gc];
#pragma unroll
      for (int j = 0; j < 4; ++j)
        outF[(size_t)(nb + j) * 256 + gc] = acc[ct][j] + bv;
    }
  }
}

// ---------------- finalize: combined Q-side scale c = temp*log2e/(|q||k|) ----
__global__ __launch_bounds__(512) void k_norm2(
    const float* __restrict__ partQ, const float* __restrict__ partK,
    const float* __restrict__ temp, f16* __restrict__ cqh)
{
  const int t = threadIdx.x;            // 512 = 8 bh * 64 dd
  const int bh = t >> 6, dd = t & 63;
  float sq = 0.f, sk = 0.f;
  for (int s = 0; s < 64; ++s) {
    sq += partQ[(bh * 64 + s) * 64 + dd];
    sk += partK[(bh * 64 + s) * 64 + dd];
  }
  float c = temp[bh & 3] * 1.4426950408889634f /
            (fmaxf(sqrtf(sq), 1e-12f) * fmaxf(sqrtf(sk), 1e-12f));
  cqh[t] = (f16)c;
}

// ---------------- flash attention v6: QBLK=64, 512 blocks, 2 blocks/CU --------
// 8 waves = 4 ks x 2 qh; wave owns 32 keys x 32 queries per 128-key tile.
// Cross-block TLP (independent barriers) hides the QK->exp->PV chain.
__device__ inline void plane_swap(u32& a, u32& b) {
  asm volatile("v_permlane32_swap_b32 %0, %1" : "+v"(a), "+v"(b));
}

__global__ __launch_bounds__(512, 4) void k_flash6(
    const f16* __restrict__ Qb, const f16* __restrict__ Kb,
    const f16* __restrict__ Vtb, const f16* __restrict__ cqh,
    f16* __restrict__ Y)
{
  __shared__ f16 KVl[32768];    // 2 x (K 128x64 | V 64x128) = 64KB; epilogue alias
  __shared__ float Lsh[256];    // [w][32 q] row sums
  const int t = threadIdx.x, w = t >> 6, l = t & 63;
  const int r = l & 31, hi = l >> 5;
  const int ks = w >> 1, qh = w & 1;
  const int r7 = r & 7;
  // XCD-bijective swizzle: 512 blocks, each XCD owns one (b,h)
  int nb2 = (blockIdx.x & 7) * 64 + (blockIdx.x >> 3);
  const int bh = nb2 >> 6, qt = nb2 & 63;
  const size_t base = (size_t)bh * NTOK * 64;
  // Q fragments (1 set of 32 q), scaled by combined per-d factor c
  f16x8 qf0, qf1, qf2, qf3;
  {
    const f16* cq = cqh + bh * 64;
    const f16* qp = Qb + base + (size_t)(qt * 64 + qh * 32 + r) * 64 + hi * 8;
    qf0 = *(const f16x8*)(qp)      * *(const f16x8*)(cq +  0 + hi * 8);
    qf1 = *(const f16x8*)(qp + 16) * *(const f16x8*)(cq + 16 + hi * 8);
    qf2 = *(const f16x8*)(qp + 32) * *(const f16x8*)(cq + 32 + hi * 8);
    qf3 = *(const f16x8*)(qp + 48) * *(const f16x8*)(cq + 48 + hi * 8);
  }
  // staging source pointers (pre-swizzled global addresses, rule #21)
  const f16* srcK = Kb + base + (size_t)(w * 8 + (l >> 3)) * 64 + ((l & 7) ^ (l >> 3)) * 8;
  const int vrow = w * 4 + (l >> 4);
  const f16* srcV = Vtb + base + (size_t)vrow * 4096 + ((l & 15) ^ (vrow & 7)) * 8;
  const int dK = w * 8 * 64;
  const int dV = 8192 + w * 4 * 128;
#define STAGE(cur, tile) { \
    const f16* sk_ = srcK + (size_t)(tile) * 8192; \
    const f16* sv_ = srcV + (tile) * 128; \
    GLL(sk_,          KVl + (cur) * 16384 + dK); \
    GLL(sk_ + 4096,   KVl + (cur) * 16384 + dK + 4096); \
    GLL(sv_,          KVl + (cur) * 16384 + dV); \
    GLL(sv_ + 131072, KVl + (cur) * 16384 + dV + 4096); }
  // fragment read offsets (f16 units, constant across stages)
  const int kro = (ks * 32 + r) * 64;
  const int kc0 = ((0 + hi) ^ r7) * 8, kc1 = ((2 + hi) ^ r7) * 8;
  const int kc2 = ((4 + hi) ^ r7) * 8, kc3 = ((6 + hi) ^ r7) * 8;
  const int vb0 = 8192 + r * 128, vb1 = 8192 + (32 + r) * 128;
  const int vc0 = ((ks * 4 + 0 + hi) ^ r7) * 8, vc1 = ((ks * 4 + 2 + hi) ^ r7) * 8;

  f32x16 oacc0 = {}, oacc1 = {};
  float lsw = 0.f;
  STAGE(0, 0);
  __syncthreads();
  for (int tl = 0; tl < 32; ++tl) {
    const int cur = tl & 1;
    const f16* Bb = KVl + cur * 16384;
    f16x8 kf0 = *(const f16x8*)(Bb + kro + kc0);
    f16x8 kf1 = *(const f16x8*)(Bb + kro + kc1);
    f16x8 kf2 = *(const f16x8*)(Bb + kro + kc2);
    f16x8 kf3 = *(const f16x8*)(Bb + kro + kc3);
    f16x8 vf0 = *(const f16x8*)(Bb + vb0 + vc0);
    f16x8 vf1 = *(const f16x8*)(Bb + vb0 + vc1);
    f16x8 vf2 = *(const f16x8*)(Bb + vb1 + vc0);
    f16x8 vf3 = *(const f16x8*)(Bb + vb1 + vc1);
    if (tl < 31) STAGE(cur ^ 1, tl + 1);
    // QK^T
    f32x16 sacc = {};
    __builtin_amdgcn_s_setprio(1);
    sacc = __builtin_amdgcn_mfma_f32_32x32x16_f16(kf0, qf0, sacc, 0, 0, 0);
    sacc = __builtin_amdgcn_mfma_f32_32x32x16_f16(kf1, qf1, sacc, 0, 0, 0);
    sacc = __builtin_amdgcn_mfma_f32_32x32x16_f16(kf2, qf2, sacc, 0, 0, 0);
    sacc = __builtin_amdgcn_mfma_f32_32x32x16_f16(kf3, qf3, sacc, 0, 0, 0);
    __builtin_amdgcn_s_setprio(0);
    // softmax in-register: exp2, pack, permlane redistribute
    u32 Dw[8];
#pragma unroll
    for (int u = 0; u < 4; ++u) {
#pragma unroll
      for (int v = 0; v < 2; ++v) {
        float a  = __builtin_amdgcn_exp2f(sacc[u * 4 + v * 2]);
        float b2 = __builtin_amdgcn_exp2f(sacc[u * 4 + v * 2 + 1]);
        lsw += a + b2;
        union { fp16x2 h; u32 u; } cv;
        cv.h = __builtin_amdgcn_cvt_pkrtz(a, b2);
        Dw[u * 2 + v] = cv.u;
      }
    }
    plane_swap(Dw[0], Dw[2]);
    plane_swap(Dw[1], Dw[3]);
    plane_swap(Dw[4], Dw[6]);
    plane_swap(Dw[5], Dw[7]);
    union { f16x8 v; u32 d[4]; } p0, p1;
    p0.d[0] = Dw[0]; p0.d[1] = Dw[1]; p0.d[2] = Dw[2]; p0.d[3] = Dw[3];
    p1.d[0] = Dw[4]; p1.d[1] = Dw[5]; p1.d[2] = Dw[6]; p1.d[3] = Dw[7];
    // PV
    __builtin_amdgcn_s_setprio(1);
    oacc0 = __builtin_amdgcn_mfma_f32_32x32x16_f16(p0.v, vf0, oacc0, 0, 0, 0);
    oacc0 = __builtin_amdgcn_mfma_f32_32x32x16_f16(p1.v, vf1, oacc0, 0, 0, 0);
    oacc1 = __builtin_amdgcn_mfma_f32_32x32x16_f16(p0.v, vf2, oacc1, 0, 0, 0);
    oacc1 = __builtin_amdgcn_mfma_f32_32x32x16_f16(p1.v, vf3, oacc1, 0, 0, 0);
    __builtin_amdgcn_s_setprio(0);
    __syncthreads();
  }
#undef STAGE
  // ---- epilogue: combine 4 key-slice partials via LDS (alias of KVl) ----
  lsw += __shfl_xor(lsw, 32, 64);
  if (hi == 0) Lsh[w * 32 + r] = lsw;
#pragma unroll
  for (int dt = 0; dt < 2; ++dt) {
    f16* orow = KVl + w * 2048 + (dt * 32 + r) * 32;
    const f32x16& oa = dt ? oacc1 : oacc0;
#pragma unroll
    for (int u = 0; u < 4; ++u) {
      f16x4 h4;
      h4[0] = (f16)oa[u * 4 + 0]; h4[1] = (f16)oa[u * 4 + 1];
      h4[2] = (f16)oa[u * 4 + 2]; h4[3] = (f16)oa[u * 4 + 3];
      *(f16x4*)(orow + ((u ^ (r & 3)) * 8) + hi * 4) = h4;
    }
  }
  __syncthreads();
  // combine: wave w = (s2 q-16-group-pair, dt2 dd-half, qh2 q-half)
  const int s2 = w >> 2, dt2 = (w >> 1) & 1, qh2 = w & 1;
  const int g = s2 * 2 + hi;    // q 8-group within 32-half
  const int b = bh >> 2, h = bh & 3;
  float accv[8] = {}, denv[8] = {};
#pragma unroll
  for (int ksl = 0; ksl < 4; ++ksl) {
    const int wp = ksl * 2 + qh2;
    f16x8 rd = *(const f16x8*)(KVl + wp * 2048 + (dt2 * 32 + r) * 32 + ((g ^ (r & 3)) * 8));
    f32x4 la = *(const f32x4*)(Lsh + wp * 32 + g * 8);
    f32x4 lb = *(const f32x4*)(Lsh + wp * 32 + g * 8 + 4);
#pragma unroll
    for (int j = 0; j < 4; ++j) {
      accv[j]     += (float)rd[j];
      accv[4 + j] += (float)rd[4 + j];
      denv[j]     += la[j];
      denv[4 + j] += lb[j];
    }
  }
  const int ng = qt * 64 + qh2 * 32 + g * 8;
  const int np = (dt2 * 32 + r) * 64 + h * 16 + (ng >> 8);
  const int cp_ = ng & 255;
  f16x8 yv;
#pragma unroll
  for (int j = 0; j < 8; ++j) yv[j] = (f16)(accv[j] / denv[j]);
  *(f16x8*)(Y + ((size_t)b * 4096 + np) * 256 + cp_) = yv;
}

extern "C" void kernel_launch(void* const* d_in, const int* in_sizes, int n_in,
                              void* d_out, int out_size, void* d_ws, size_t ws_size,
                              hipStream_t stream)
{
  const float* x     = (const float*)d_in[0];   // [2,4096,256]
  const float* w_qkv = (const float*)d_in[1];   // [768,256]
  const float* w_out = (const float*)d_in[2];   // [256,256]
  const float* b_out = (const float*)d_in[3];   // [256]
  const float* temp  = (const float*)d_in[4];   // [4,1,1]

  char* ws = (char*)d_ws;
  f16*   xb    = (f16*)(ws);                                  // 4MB
  f16*   wqkvb = (f16*)(ws + 4 * 1024 * 1024);
  f16*   woutb = (f16*)(ws + 4 * 1024 * 1024 + 512 * 1024);
  f16*   Qb    = (f16*)(ws + 5  * 1024 * 1024);               // [8][4096][64]
  f16*   Kb    = (f16*)(ws + 9  * 1024 * 1024);
  f16*   Vtb   = (f16*)(ws + 13 * 1024 * 1024);               // [8][64][4096]
  f16*   cqh   = (f16*)(ws + 17 * 1024 * 1024);               // 512 f16
  float* partQ = (float*)(ws + 17 * 1024 * 1024 + 8192);      // 128KB
  float* partK = (float*)(ws + 17 * 1024 * 1024 + 8192 + 131072);
  f16*   Y     = (f16*)(ws + 18 * 1024 * 1024);               // [2][4096][256]
  float* outF  = (float*)d_out;

  k_cvt<<<2304, 256, 0, stream>>>(x, w_qkv, w_out, xb, wqkvb, woutb);
  k_gemm<<<dim3(12, 128), 256, 0, stream>>>(xb, wqkvb, 256, 0, Qb, Kb, Vtb,
                                            nullptr, nullptr, partQ, partK);
  k_norm2<<<1, 512, 0, stream>>>(partQ, partK, temp, cqh);
  k_flash6<<<512, 512, 0, stream>>>(Qb, Kb, Vtb, cqh, Y);
  k_gemm<<<dim3(4, 128), 256, 0, stream>>>(Y, woutb, 256, 1, nullptr, nullptr, nullptr,
                                           outF, b_out, nullptr, nullptr);
}